// Round 18
// baseline (23.142 us; speedup 1.0000x reference)
//
#include <hip/hip_runtime.h>
#include <hip/hip_bf16.h>
#include <math.h>

// TTMultiheadAttention via MFMA (round 16 = round 12 + 32KB LDS for co-residency):
//   per s:  G_i[e,d] = sum_q brs_i[e,q] * x[q,s,d]      (mfma 32x32x16 bf16)
//           P_i = exp2(G_i)
//           OUT_i[b,d] = sum_e CrT_sigma[b,e] * P_i[e,d] (mfma, row16=ones -> l_i)
//           out[b,s,d] = sum_i OUT_i[b,d] / l_i[d]
// Round-16 change (r15 exonerated staging; r8 occupancy 26% = 2 blocks/CU
// despite VGPR 52: LDS 40960x4 = EXACTLY 160KB, zero headroom -> suspect
// exact-fit/reservation drops co-residency, so per-block serial segments
// can't overlap): LDS 40960 -> 32768 B exactly.
//  (a) cr units compacted 32 rows -> 16 real rows (stride 256 ushorts);
//      read addr (lane&31)*8 + (lane>>5)*128; A-rows 17..31 = garbage reads
//      (harmless: MFMA output rows independent, acc rows >16 never read).
//  (b) ones-row (A-row 16, lanes 16/48) injected via v_cndmask on the loaded
//      fragment (2/load, ~64 VALU/wave) instead of LDS -> acc[8] still = l_i.
// cr region first; its garbage tail reads land in br data (in-bounds).
// Compute math bit-identical to r12 (22.66us best).

#define SS 512
#define DD 256
#define R2 16
#define NI 3

#define CR_USH   4096                        // 16 units x 256 ushorts (8 KB)
#define BR_BASE  4096                        // br after cr
#define BR_USH_N (NI * 8 * 512)              // 12288 ushorts (24 KB)
#define WS_USH   (CR_USH + BR_USH_N)         // 16384 ushorts = 32768 B EXACT
#define ALL_UNITS (WS_USH / 8)               // 2048 x 16B

typedef __attribute__((ext_vector_type(8))) short bf16x8;
typedef __attribute__((ext_vector_type(8))) unsigned short ushort8;
typedef __attribute__((ext_vector_type(16))) float f32x16;
typedef __attribute__((ext_vector_type(2))) unsigned uint2v;

union B8 { unsigned w[4]; bf16x8 v; };

static __device__ __forceinline__ unsigned short bf16bits(float f) {
    union { __hip_bfloat16 h; unsigned short u; } c;
    c.h = __float2bfloat16(f);
    return c.u;
}
static __device__ __forceinline__ unsigned packb(float a, float b) {
    union { __hip_bfloat162 h; unsigned u; } c;
    c.h = __float22bfloat162_rn(make_float2(a, b));
    return c.u;
}
// ONE-instruction pack: dst = {b[31:16], a[31:16]} = {bf16_trunc(b), bf16_trunc(a)}
static __device__ __forceinline__ unsigned permpack(float a, float b) {
    union { float f; unsigned u; } ua, ub;
    ua.f = a; ub.f = b;
    return __builtin_amdgcn_perm(ub.u, ua.u, 0x07060302u);
}

// Workspace layout (matches LDS byte-for-byte):
//  cr  (ushort 0..4095):    unit u = et*2+h (16 units, stride 256), slot s=0..31:
//    b = s&15, hi = s>>4;  crf[u*256 + s*8 + j] = bf16(cr[b][e]),
//    e = et*32 + h*16 + (j&3) + 8*(j>>2) + 4*hi      (sigma k-slot permutation)
//  br  (ushort 4096..16383): brf[4096 + ((i*8+et)*64+l)*8 + j]
//    = bf16(br[i][et*32+(l&31)][8*(l>>5)+j] * cA2_i)
__global__ void tt_prep(const float* __restrict__ ar,
                        const float* __restrict__ br,
                        const float* __restrict__ cr,
                        unsigned short* __restrict__ wsf)
{
    const int t = blockIdx.x * 256 + threadIdx.x;   // 0..2047
    float cA2[NI];
#pragma unroll
    for (int i = 0; i < NI; ++i) {
        float A = ar[0 * NI + i] + ar[1 * NI + i] + ar[2 * NI + i];
        cA2[i] = A * (0.17677669529663687f * 1.4426950408889634f);
    }
    if (t < 512) {                                  // cr region: 16 units x 32 slots
        const int u = t >> 5, slot = t & 31;
        const int b = slot & 15, hi2 = slot >> 4;
        const int et = u >> 1, h = u & 1;
        ushort8 v;
#pragma unroll
        for (int j = 0; j < 8; ++j) {
            const int e = et * 32 + h * 16 + (j & 3) + 8 * (j >> 2) + 4 * hi2;
            v[j] = bf16bits(cr[b * DD + e]);
        }
        *(ushort8*)(wsf + (u << 8) + (slot << 3)) = v;
    } else {                                        // br region
        const int idx = t - 512;                    // 0..1535
        const int l = idx & 63, et = (idx >> 6) & 7, i = idx >> 9;
        const float* src = br + (i * DD + et * 32 + (l & 31)) * R2 + 8 * (l >> 5);
        const float sc = cA2[i];
        ushort8 v;
#pragma unroll
        for (int j = 0; j < 8; ++j) v[j] = bf16bits(src[j] * sc);
        *(ushort8*)(wsf + BR_BASE + idx * 8) = v;
    }
}

__global__ __launch_bounds__(256, 4) void tt_attn_mfma(
    const float* __restrict__ x,
    const unsigned short* __restrict__ wsf,
    float* __restrict__ out)
{
    __shared__ unsigned short lds[WS_USH];          // 32768 B exactly

    const int s     = blockIdx.x >> 1;
    const int dhalf = blockIdx.x & 1;
    const int tid   = threadIdx.x;
    const int lane  = tid & 63;
    const int wv    = tid >> 6;
    const int hi    = lane >> 5;
    const int d     = dhalf * 128 + wv * 32 + (lane & 31);

    // Stage weights to LDS: 8 chunks x 256 threads x 16 B = 32 KB.
#pragma unroll
    for (int c = 0; c < 8; ++c) {
        const char* g = (const char*)wsf + (size_t)(c * 256 + tid) * 16;
        char* lp = (char*)lds + (size_t)(c * 256 + wv * 64) * 16;
        __builtin_amdgcn_global_load_lds(
            (const __attribute__((address_space(1))) void*)g,
            (__attribute__((address_space(3))) void*)lp, 16, 0, 0);
    }

    // x fragment (issues while LDS staging is in flight):
    // lane holds x[q = 8*hi + j][s][d]  (B-operand of stage 1)
    const float* xp = x + s * DD + d + (hi ? 8 * SS * DD : 0);
    float xr[8];
#pragma unroll
    for (int t = 0; t < 8; ++t) xr[t] = xp[t * SS * DD];
    B8 xb;
#pragma unroll
    for (int t = 0; t < 4; ++t) xb.w[t] = packb(xr[2 * t], xr[2 * t + 1]);  // RNE (once)
    const bf16x8 xf = xb.v;

    __syncthreads();   // drains vmcnt (global_load_lds) per compiler semantics

    f32x16 acc0{}, acc1{}, acc2{};
    const f32x16 zf{};

    // cr unit read base: lane row b = lane&31 (rows >16 read harmless garbage);
    // hi half offset 128 ushorts. br base unchanged (dense 64-lane layout).
    const unsigned short* crl = lds + (lane & 31) * 8 + (lane >> 5) * 128;
    const unsigned short* brl = lds + BR_BASE + lane * 8;
    const bool isones = ((lane & 31) == 16);        // A-row 16 lanes (16 and 48)
    const unsigned onepat = 0x3F803F80u;            // {bf16(1), bf16(1)}

#pragma unroll 2
    for (int et = 0; et < 8; ++et) {
        B8 c0, c1;
        c0.v = *(const bf16x8*)(crl + (et * 2 + 0) * 256);
        c1.v = *(const bf16x8*)(crl + (et * 2 + 1) * 256);
#pragma unroll
        for (int t = 0; t < 4; ++t) {               // inject ones-row (2 cndmask/frag)
            c0.w[t] = isones ? onepat : c0.w[t];
            c1.w[t] = isones ? onepat : c1.w[t];
        }
        const bf16x8 crA0 = c0.v, crA1 = c1.v;
#pragma unroll
        for (int i = 0; i < NI; ++i) {
            const bf16x8 brA = *(const bf16x8*)(brl + (i * 8 + et) * 512);
            f32x16 g = __builtin_amdgcn_mfma_f32_32x32x16_bf16(brA, xf, zf, 0, 0, 0);
            float p[16];
#pragma unroll
            for (int r = 0; r < 16; ++r) p[r] = __builtin_amdgcn_exp2f(g[r]);
            // packs feed stage-2 B operand DIRECTLY (k-slots sigma-permuted on A side)
            B8 P0, P1;
            P0.w[0] = permpack(p[0],  p[1]);
            P0.w[1] = permpack(p[2],  p[3]);
            P0.w[2] = permpack(p[4],  p[5]);
            P0.w[3] = permpack(p[6],  p[7]);
            P1.w[0] = permpack(p[8],  p[9]);
            P1.w[1] = permpack(p[10], p[11]);
            P1.w[2] = permpack(p[12], p[13]);
            P1.w[3] = permpack(p[14], p[15]);
            if (i == 0) {
                acc0 = __builtin_amdgcn_mfma_f32_32x32x16_bf16(crA0, P0.v, acc0, 0, 0, 0);
                acc0 = __builtin_amdgcn_mfma_f32_32x32x16_bf16(crA1, P1.v, acc0, 0, 0, 0);
            } else if (i == 1) {
                acc1 = __builtin_amdgcn_mfma_f32_32x32x16_bf16(crA0, P0.v, acc1, 0, 0, 0);
                acc1 = __builtin_amdgcn_mfma_f32_32x32x16_bf16(crA1, P1.v, acc1, 0, 0, 0);
            } else {
                acc2 = __builtin_amdgcn_mfma_f32_32x32x16_bf16(crA0, P0.v, acc2, 0, 0, 0);
                acc2 = __builtin_amdgcn_mfma_f32_32x32x16_bf16(crA1, P1.v, acc2, 0, 0, 0);
            }
        }
    }

    // l_i sits in C row 16 = reg 8 of hi=0 lanes; broadcast to hi=1 half
    float inv[NI];
#pragma unroll
    for (int i = 0; i < NI; ++i) {
        union { float f; unsigned u; } c;
        c.f = (i == 0) ? acc0[8] : (i == 1) ? acc1[8] : acc2[8];
        const uint2v r = __builtin_amdgcn_permlane32_swap(c.u, c.u, false, false);
        union { unsigned u; float f; } c2; c2.u = r.x;
        inv[i] = 1.0f / c2.f;
    }

#pragma unroll
    for (int r = 0; r < 8; ++r) {
        const int b = (r & 3) + 8 * (r >> 2) + 4 * hi;
        const float o = acc0[r] * inv[0] + acc1[r] * inv[1] + acc2[r] * inv[2];
        out[(b * SS + s) * DD + d] = o;
    }
}

extern "C" void kernel_launch(void* const* d_in, const int* in_sizes, int n_in,
                              void* d_out, int out_size, void* d_ws, size_t ws_size,
                              hipStream_t stream) {
    const float* x  = (const float*)d_in[0];
    const float* ar = (const float*)d_in[1];
    const float* br = (const float*)d_in[2];
    const float* cr = (const float*)d_in[3];
    float* out = (float*)d_out;

    unsigned short* wsf = (unsigned short*)d_ws;   // 32 KB: cr (8K) then br (24K)

    hipLaunchKernelGGL(tt_prep, dim3(8), dim3(256), 0, stream, ar, br, cr, wsf);
    hipLaunchKernelGGL(tt_attn_mfma, dim3(SS * 2), dim3(256), 0, stream, x, wsf, out);
}

// Round 19
// 22.703 us; speedup vs baseline: 1.0193x; 1.0193x over previous
//
#include <hip/hip_runtime.h>
#include <hip/hip_bf16.h>
#include <math.h>

// TTMultiheadAttention via MFMA (round 16 = round 12 + 32KB LDS for co-residency):
//   per s:  G_i[e,d] = sum_q brs_i[e,q] * x[q,s,d]      (mfma 32x32x16 bf16)
//           P_i = exp2(G_i)
//           OUT_i[b,d] = sum_e CrT_sigma[b,e] * P_i[e,d] (mfma, row16=ones -> l_i)
//           out[b,s,d] = sum_i OUT_i[b,d] / l_i[d]
// Round-16 change (r15 exonerated staging; r8 occupancy 26% = 2 blocks/CU
// despite VGPR 52: LDS 40960x4 = EXACTLY 160KB, zero headroom -> suspect
// exact-fit/reservation drops co-residency, so per-block serial segments
// can't overlap): LDS 40960 -> 32768 B exactly.
//  (a) cr units compacted 32 rows -> 16 real rows (stride 256 ushorts);
//      read addr (lane&31)*8 + (lane>>5)*128; A-rows 17..31 = garbage reads
//      (harmless: MFMA output rows independent, acc rows >16 never read).
//  (b) ones-row (A-row 16, lanes 16/48) injected via v_cndmask on the loaded
//      fragment (2/load, ~64 VALU/wave) instead of LDS -> acc[8] still = l_i.
// cr region first; its garbage tail reads land in br data (in-bounds).
// Compute math bit-identical to r12 (22.66us best).

#define SS 512
#define DD 256
#define R2 16
#define NI 3

#define CR_USH   4096                        // 16 units x 256 ushorts (8 KB)
#define BR_BASE  4096                        // br after cr
#define BR_USH_N (NI * 8 * 512)              // 12288 ushorts (24 KB)
#define WS_USH   (CR_USH + BR_USH_N)         // 16384 ushorts = 32768 B EXACT
#define ALL_UNITS (WS_USH / 8)               // 2048 x 16B

typedef __attribute__((ext_vector_type(8))) short bf16x8;
typedef __attribute__((ext_vector_type(8))) unsigned short ushort8;
typedef __attribute__((ext_vector_type(16))) float f32x16;
typedef __attribute__((ext_vector_type(2))) unsigned uint2v;

union B8 { unsigned w[4]; bf16x8 v; };

static __device__ __forceinline__ unsigned short bf16bits(float f) {
    union { __hip_bfloat16 h; unsigned short u; } c;
    c.h = __float2bfloat16(f);
    return c.u;
}
static __device__ __forceinline__ unsigned packb(float a, float b) {
    union { __hip_bfloat162 h; unsigned u; } c;
    c.h = __float22bfloat162_rn(make_float2(a, b));
    return c.u;
}
// ONE-instruction pack: dst = {b[31:16], a[31:16]} = {bf16_trunc(b), bf16_trunc(a)}
static __device__ __forceinline__ unsigned permpack(float a, float b) {
    union { float f; unsigned u; } ua, ub;
    ua.f = a; ub.f = b;
    return __builtin_amdgcn_perm(ub.u, ua.u, 0x07060302u);
}

// Workspace layout (matches LDS byte-for-byte):
//  cr  (ushort 0..4095):    unit u = et*2+h (16 units, stride 256), slot s=0..31:
//    b = s&15, hi = s>>4;  crf[u*256 + s*8 + j] = bf16(cr[b][e]),
//    e = et*32 + h*16 + (j&3) + 8*(j>>2) + 4*hi      (sigma k-slot permutation)
//  br  (ushort 4096..16383): brf[4096 + ((i*8+et)*64+l)*8 + j]
//    = bf16(br[i][et*32+(l&31)][8*(l>>5)+j] * cA2_i)
__global__ void tt_prep(const float* __restrict__ ar,
                        const float* __restrict__ br,
                        const float* __restrict__ cr,
                        unsigned short* __restrict__ wsf)
{
    const int t = blockIdx.x * 256 + threadIdx.x;   // 0..2047
    float cA2[NI];
#pragma unroll
    for (int i = 0; i < NI; ++i) {
        float A = ar[0 * NI + i] + ar[1 * NI + i] + ar[2 * NI + i];
        cA2[i] = A * (0.17677669529663687f * 1.4426950408889634f);
    }
    if (t < 512) {                                  // cr region: 16 units x 32 slots
        const int u = t >> 5, slot = t & 31;
        const int b = slot & 15, hi2 = slot >> 4;
        const int et = u >> 1, h = u & 1;
        ushort8 v;
#pragma unroll
        for (int j = 0; j < 8; ++j) {
            const int e = et * 32 + h * 16 + (j & 3) + 8 * (j >> 2) + 4 * hi2;
            v[j] = bf16bits(cr[b * DD + e]);
        }
        *(ushort8*)(wsf + (u << 8) + (slot << 3)) = v;
    } else {                                        // br region
        const int idx = t - 512;                    // 0..1535
        const int l = idx & 63, et = (idx >> 6) & 7, i = idx >> 9;
        const float* src = br + (i * DD + et * 32 + (l & 31)) * R2 + 8 * (l >> 5);
        const float sc = cA2[i];
        ushort8 v;
#pragma unroll
        for (int j = 0; j < 8; ++j) v[j] = bf16bits(src[j] * sc);
        *(ushort8*)(wsf + BR_BASE + idx * 8) = v;
    }
}

__global__ __launch_bounds__(256, 4) void tt_attn_mfma(
    const float* __restrict__ x,
    const unsigned short* __restrict__ wsf,
    float* __restrict__ out)
{
    __shared__ unsigned short lds[WS_USH];          // 32768 B exactly

    const int s     = blockIdx.x >> 1;
    const int dhalf = blockIdx.x & 1;
    const int tid   = threadIdx.x;
    const int lane  = tid & 63;
    const int wv    = tid >> 6;
    const int hi    = lane >> 5;
    const int d     = dhalf * 128 + wv * 32 + (lane & 31);

    // Stage weights to LDS: 8 chunks x 256 threads x 16 B = 32 KB.
#pragma unroll
    for (int c = 0; c < 8; ++c) {
        const char* g = (const char*)wsf + (size_t)(c * 256 + tid) * 16;
        char* lp = (char*)lds + (size_t)(c * 256 + wv * 64) * 16;
        __builtin_amdgcn_global_load_lds(
            (const __attribute__((address_space(1))) void*)g,
            (__attribute__((address_space(3))) void*)lp, 16, 0, 0);
    }

    // x fragment (issues while LDS staging is in flight):
    // lane holds x[q = 8*hi + j][s][d]  (B-operand of stage 1)
    const float* xp = x + s * DD + d + (hi ? 8 * SS * DD : 0);
    float xr[8];
#pragma unroll
    for (int t = 0; t < 8; ++t) xr[t] = xp[t * SS * DD];
    B8 xb;
#pragma unroll
    for (int t = 0; t < 4; ++t) xb.w[t] = packb(xr[2 * t], xr[2 * t + 1]);  // RNE (once)
    const bf16x8 xf = xb.v;

    __syncthreads();   // drains vmcnt (global_load_lds) per compiler semantics

    f32x16 acc0{}, acc1{}, acc2{};
    const f32x16 zf{};

    // cr unit read base: lane row b = lane&31 (rows >16 read harmless garbage);
    // hi half offset 128 ushorts. br base unchanged (dense 64-lane layout).
    const unsigned short* crl = lds + (lane & 31) * 8 + (lane >> 5) * 128;
    const unsigned short* brl = lds + BR_BASE + lane * 8;
    const bool isones = ((lane & 31) == 16);        // A-row 16 lanes (16 and 48)
    const unsigned onepat = 0x3F803F80u;            // {bf16(1), bf16(1)}

#pragma unroll 2
    for (int et = 0; et < 8; ++et) {
        B8 c0, c1;
        c0.v = *(const bf16x8*)(crl + (et * 2 + 0) * 256);
        c1.v = *(const bf16x8*)(crl + (et * 2 + 1) * 256);
#pragma unroll
        for (int t = 0; t < 4; ++t) {               // inject ones-row (2 cndmask/frag)
            c0.w[t] = isones ? onepat : c0.w[t];
            c1.w[t] = isones ? onepat : c1.w[t];
        }
        const bf16x8 crA0 = c0.v, crA1 = c1.v;
#pragma unroll
        for (int i = 0; i < NI; ++i) {
            const bf16x8 brA = *(const bf16x8*)(brl + (i * 8 + et) * 512);
            f32x16 g = __builtin_amdgcn_mfma_f32_32x32x16_bf16(brA, xf, zf, 0, 0, 0);
            float p[16];
#pragma unroll
            for (int r = 0; r < 16; ++r) p[r] = __builtin_amdgcn_exp2f(g[r]);
            // packs feed stage-2 B operand DIRECTLY (k-slots sigma-permuted on A side)
            B8 P0, P1;
            P0.w[0] = permpack(p[0],  p[1]);
            P0.w[1] = permpack(p[2],  p[3]);
            P0.w[2] = permpack(p[4],  p[5]);
            P0.w[3] = permpack(p[6],  p[7]);
            P1.w[0] = permpack(p[8],  p[9]);
            P1.w[1] = permpack(p[10], p[11]);
            P1.w[2] = permpack(p[12], p[13]);
            P1.w[3] = permpack(p[14], p[15]);
            if (i == 0) {
                acc0 = __builtin_amdgcn_mfma_f32_32x32x16_bf16(crA0, P0.v, acc0, 0, 0, 0);
                acc0 = __builtin_amdgcn_mfma_f32_32x32x16_bf16(crA1, P1.v, acc0, 0, 0, 0);
            } else if (i == 1) {
                acc1 = __builtin_amdgcn_mfma_f32_32x32x16_bf16(crA0, P0.v, acc1, 0, 0, 0);
                acc1 = __builtin_amdgcn_mfma_f32_32x32x16_bf16(crA1, P1.v, acc1, 0, 0, 0);
            } else {
                acc2 = __builtin_amdgcn_mfma_f32_32x32x16_bf16(crA0, P0.v, acc2, 0, 0, 0);
                acc2 = __builtin_amdgcn_mfma_f32_32x32x16_bf16(crA1, P1.v, acc2, 0, 0, 0);
            }
        }
    }

    // l_i sits in C row 16 = reg 8 of hi=0 lanes; broadcast to hi=1 half
    float inv[NI];
#pragma unroll
    for (int i = 0; i < NI; ++i) {
        union { float f; unsigned u; } c;
        c.f = (i == 0) ? acc0[8] : (i == 1) ? acc1[8] : acc2[8];
        const uint2v r = __builtin_amdgcn_permlane32_swap(c.u, c.u, false, false);
        union { unsigned u; float f; } c2; c2.u = r.x;
        inv[i] = 1.0f / c2.f;
    }

#pragma unroll
    for (int r = 0; r < 8; ++r) {
        const int b = (r & 3) + 8 * (r >> 2) + 4 * hi;
        const float o = acc0[r] * inv[0] + acc1[r] * inv[1] + acc2[r] * inv[2];
        out[(b * SS + s) * DD + d] = o;
    }
}

extern "C" void kernel_launch(void* const* d_in, const int* in_sizes, int n_in,
                              void* d_out, int out_size, void* d_ws, size_t ws_size,
                              hipStream_t stream) {
    const float* x  = (const float*)d_in[0];
    const float* ar = (const float*)d_in[1];
    const float* br = (const float*)d_in[2];
    const float* cr = (const float*)d_in[3];
    float* out = (float*)d_out;

    unsigned short* wsf = (unsigned short*)d_ws;   // 32 KB: cr (8K) then br (24K)

    hipLaunchKernelGGL(tt_prep, dim3(8), dim3(256), 0, stream, ar, br, cr, wsf);
    hipLaunchKernelGGL(tt_attn_mfma, dim3(SS * 2), dim3(256), 0, stream, x, wsf, out);
}

// Round 20
// 22.524 us; speedup vs baseline: 1.0275x; 1.0080x over previous
//
#include <hip/hip_runtime.h>
#include <hip/hip_bf16.h>
#include <math.h>

// TTMultiheadAttention via MFMA — FINAL (= round 12, proven best 22.66us):
//   per s:  G_i[e,d] = sum_q brs_i[e,q] * x[q,s,d]      (mfma 32x32x16 bf16)
//           P_i = exp2(G_i)   (brs pre-scaled by cA2_i*log2e/sqrt(32))
//           OUT_i[b,d] = sum_e CrT_sigma[b,e] * P_i[e,d] (mfma, row16=ones -> l_i)
//           out[b,s,d] = sum_i OUT_i[b,d] / l_i[d]
// Optimization history (136us -> 22.7us):
//   r3: MFMA reformulation + ones-row softmax denominator     100 -> 28.8
//   r4: global_load_lds weight staging (40KB)                 28.8 -> 27.65
//   r11: v_perm_b32 1-instr truncation pack (bias cancels
//        in softmax ratio: same P in numerator & denominator) 27.65 -> 23.7
//   r12: sigma k-slot permutation folded into CrT at prep
//        (MFMA contraction invariant under common k-perm)
//        -> zero cross-lane ops in hot loop                   23.7 -> 22.66
// Falsified for the residual ~10us: launch count, block count, occupancy,
// within-wave ILP, trans-pipe, staging/drain, LDS co-residency. Empirical
// law: wall tracks VALU instr count at ~8cyc/instr; hot loop is at the
// structural minimum (1 pack op / 2 values, exp2 on free trans pipe).

#define SS 512
#define DD 256
#define R2 16
#define NI 3

#define BR_UNITS (NI * 8 * 64)              // 1536 x 16B
#define CR_UNITS (16 * 64)                  // 1024 x 16B
#define ALL_UNITS (BR_UNITS + CR_UNITS)     // 2560 x 16B = 40 KB
#define BR_USH (BR_UNITS * 8)               // 12288 ushorts
#define WS_USH (ALL_UNITS * 8)              // 20480 ushorts

typedef __attribute__((ext_vector_type(8))) short bf16x8;
typedef __attribute__((ext_vector_type(8))) unsigned short ushort8;
typedef __attribute__((ext_vector_type(16))) float f32x16;
typedef __attribute__((ext_vector_type(2))) unsigned uint2v;

union B8 { unsigned w[4]; bf16x8 v; };

static __device__ __forceinline__ unsigned short bf16bits(float f) {
    union { __hip_bfloat16 h; unsigned short u; } c;
    c.h = __float2bfloat16(f);
    return c.u;
}
static __device__ __forceinline__ unsigned packb(float a, float b) {
    union { __hip_bfloat162 h; unsigned u; } c;
    c.h = __float22bfloat162_rn(make_float2(a, b));
    return c.u;
}
// ONE-instruction pack: dst = {b[31:16], a[31:16]} = {bf16_trunc(b), bf16_trunc(a)}
static __device__ __forceinline__ unsigned permpack(float a, float b) {
    union { float f; unsigned u; } ua, ub;
    ua.f = a; ub.f = b;
    return __builtin_amdgcn_perm(ub.u, ua.u, 0x07060302u);
}

// Fragment packing (one b128 store per thread, 2560 threads = grid 10 x 256):
// brf[((i*8+et)*64 + l)*8 + j] = bf16(br[i][et*32+(l&31)][8*(l>>5)+j] * cA2_i)
// crf: k-slot-permuted CrT (+ ones row at b==16):
//   e = et*32 + h*16 + (j&3) + 8*(j>>2) + 4*(l>>5)     <-- sigma(k-slot)
__global__ void tt_prep(const float* __restrict__ ar,
                        const float* __restrict__ br,
                        const float* __restrict__ cr,
                        unsigned short* __restrict__ wsf)
{
    const int t = blockIdx.x * 256 + threadIdx.x;   // 0..2559
    float cA2[NI];
#pragma unroll
    for (int i = 0; i < NI; ++i) {
        float A = ar[0 * NI + i] + ar[1 * NI + i] + ar[2 * NI + i];
        cA2[i] = A * (0.17677669529663687f * 1.4426950408889634f);
    }
    if (t < BR_UNITS) {
        const int l = t & 63, et = (t >> 6) & 7, i = t >> 9;
        const float* src = br + (i * DD + et * 32 + (l & 31)) * R2 + 8 * (l >> 5);
        const float sc = cA2[i];
        ushort8 v;
#pragma unroll
        for (int j = 0; j < 8; ++j) v[j] = bf16bits(src[j] * sc);
        *(ushort8*)(wsf + t * 8) = v;
    } else {
        const int idx = t - BR_UNITS;               // 0..1023
        const int l = idx & 63, h = (idx >> 6) & 1, et = idx >> 7;
        const int b = l & 31;
        ushort8 v;
#pragma unroll
        for (int j = 0; j < 8; ++j) {
            const int e = et * 32 + h * 16 + (j & 3) + 8 * (j >> 2) + 4 * (l >> 5);
            float val = (b < 16) ? cr[b * DD + e] : (b == 16 ? 1.0f : 0.0f);
            v[j] = bf16bits(val);
        }
        *(ushort8*)(wsf + (BR_USH + idx * 8)) = v;
    }
}

__global__ __launch_bounds__(256, 4) void tt_attn_mfma(
    const float* __restrict__ x,
    const unsigned short* __restrict__ wsf,
    float* __restrict__ out)
{
    __shared__ unsigned short lds[WS_USH];          // 40960 B: 4 blocks/CU

    const int s     = blockIdx.x >> 1;
    const int dhalf = blockIdx.x & 1;
    const int tid   = threadIdx.x;
    const int lane  = tid & 63;
    const int wv    = tid >> 6;
    const int hi    = lane >> 5;
    const int d     = dhalf * 128 + wv * 32 + (lane & 31);

    // Stage all weight fragments to LDS: 10 chunks x 256 threads x 16 B = 40 KB.
#pragma unroll
    for (int c = 0; c < 10; ++c) {
        const char* g = (const char*)wsf + (size_t)(c * 256 + tid) * 16;
        char* lp = (char*)lds + (size_t)(c * 256 + wv * 64) * 16;
        __builtin_amdgcn_global_load_lds(
            (const __attribute__((address_space(1))) void*)g,
            (__attribute__((address_space(3))) void*)lp, 16, 0, 0);
    }

    // x fragment (issues while LDS staging is in flight):
    // lane holds x[q = 8*hi + j][s][d]  (B-operand of stage 1)
    const float* xp = x + s * DD + d + (hi ? 8 * SS * DD : 0);
    float xr[8];
#pragma unroll
    for (int t = 0; t < 8; ++t) xr[t] = xp[t * SS * DD];
    B8 xb;
#pragma unroll
    for (int t = 0; t < 4; ++t) xb.w[t] = packb(xr[2 * t], xr[2 * t + 1]);  // RNE (once)
    const bf16x8 xf = xb.v;

    __syncthreads();   // drains vmcnt (global_load_lds) per compiler semantics

    f32x16 acc0{}, acc1{}, acc2{};
    const f32x16 zf{};

    const unsigned short* brl = lds + lane * 8;
    const unsigned short* crl = lds + BR_USH + lane * 8;

#pragma unroll 2
    for (int et = 0; et < 8; ++et) {
        const bf16x8 crA0 = *(const bf16x8*)(crl + (et * 2 + 0) * 512);
        const bf16x8 crA1 = *(const bf16x8*)(crl + (et * 2 + 1) * 512);
#pragma unroll
        for (int i = 0; i < NI; ++i) {
            const bf16x8 brA = *(const bf16x8*)(brl + (i * 8 + et) * 512);
            f32x16 g = __builtin_amdgcn_mfma_f32_32x32x16_bf16(brA, xf, zf, 0, 0, 0);
            float p[16];
#pragma unroll
            for (int r = 0; r < 16; ++r) p[r] = __builtin_amdgcn_exp2f(g[r]);
            // packs feed stage-2 B operand DIRECTLY (k-slots sigma-permuted on A side)
            B8 P0, P1;
            P0.w[0] = permpack(p[0],  p[1]);
            P0.w[1] = permpack(p[2],  p[3]);
            P0.w[2] = permpack(p[4],  p[5]);
            P0.w[3] = permpack(p[6],  p[7]);
            P1.w[0] = permpack(p[8],  p[9]);
            P1.w[1] = permpack(p[10], p[11]);
            P1.w[2] = permpack(p[12], p[13]);
            P1.w[3] = permpack(p[14], p[15]);
            if (i == 0) {
                acc0 = __builtin_amdgcn_mfma_f32_32x32x16_bf16(crA0, P0.v, acc0, 0, 0, 0);
                acc0 = __builtin_amdgcn_mfma_f32_32x32x16_bf16(crA1, P1.v, acc0, 0, 0, 0);
            } else if (i == 1) {
                acc1 = __builtin_amdgcn_mfma_f32_32x32x16_bf16(crA0, P0.v, acc1, 0, 0, 0);
                acc1 = __builtin_amdgcn_mfma_f32_32x32x16_bf16(crA1, P1.v, acc1, 0, 0, 0);
            } else {
                acc2 = __builtin_amdgcn_mfma_f32_32x32x16_bf16(crA0, P0.v, acc2, 0, 0, 0);
                acc2 = __builtin_amdgcn_mfma_f32_32x32x16_bf16(crA1, P1.v, acc2, 0, 0, 0);
            }
        }
    }

    // l_i sits in C row 16 = reg 8 of hi=0 lanes; broadcast to hi=1 half
    float inv[NI];
#pragma unroll
    for (int i = 0; i < NI; ++i) {
        union { float f; unsigned u; } c;
        c.f = (i == 0) ? acc0[8] : (i == 1) ? acc1[8] : acc2[8];
        const uint2v r = __builtin_amdgcn_permlane32_swap(c.u, c.u, false, false);
        union { unsigned u; float f; } c2; c2.u = r.x;
        inv[i] = 1.0f / c2.f;
    }

#pragma unroll
    for (int r = 0; r < 8; ++r) {
        const int b = (r & 3) + 8 * (r >> 2) + 4 * hi;
        const float o = acc0[r] * inv[0] + acc1[r] * inv[1] + acc2[r] * inv[2];
        out[(b * SS + s) * DD + d] = o;
    }
}

extern "C" void kernel_launch(void* const* d_in, const int* in_sizes, int n_in,
                              void* d_out, int out_size, void* d_ws, size_t ws_size,
                              hipStream_t stream) {
    const float* x  = (const float*)d_in[0];
    const float* ar = (const float*)d_in[1];
    const float* br = (const float*)d_in[2];
    const float* cr = (const float*)d_in[3];
    float* out = (float*)d_out;

    unsigned short* wsf = (unsigned short*)d_ws;   // 40 KB: brf (24K) then crf (16K)

    hipLaunchKernelGGL(tt_prep, dim3(10), dim3(256), 0, stream, ar, br, cr, wsf);
    hipLaunchKernelGGL(tt_attn_mfma, dim3(SS * 2), dim3(256), 0, stream, x, wsf, out);
}